// Round 4
// baseline (360.041 us; speedup 1.0000x reference)
//
#include <hip/hip_runtime.h>
#include <math.h>

// Problem constants (from reference)
constexpr int B_SZ = 16384;
constexpr long long CELLS = 4194304;   // 16384*256 cells, 2 anchor slots each
constexpr int CLS_CELLS = 8192;        // logits[:batch_size] -> first 8192 cells get cls loss
constexpr float NOOBJ_SCALE = 0.5f;
constexpr float COORD_SCALE = 5.0f;

constexpr int TPB = 256;               // threads per block == cells per tile
constexpr int NBLOCKS = 2048;          // 8 blocks/CU worth of work, 7 resident (LDS-limited)
constexpr int TILES = 16384 / NBLOCKS; // 8 tiles per block, interleaved by NBLOCKS
constexpr int PRED_PITCH = 13;         // 12 floats + 1 pad (odd stride -> 2-way LDS = free)
constexpr int TGT_PITCH  = 9;          // 8 floats + 1 pad
constexpr int NSLOTS = 64;             // atomic scatter slots in d_ws

// Per-(cell,slot) loss contribution.
// pred slot layout: offset=p0, dur=p1, conf=p2, cls=p3..p5  (slot1: +6)
// target slot layout: conf, cls, offset, dur                (slot1: +4)
__device__ __forceinline__ float slot_loss(float pc, float l0, float l1, float l2,
                                           float po, float pd,
                                           float tc, float tcls, float to, float td,
                                           bool do_cls) {
    float d = tc - pc;
    bool obj = (tc == 1.0f);
    float w = obj ? 1.0f : ((tc == 0.0f) ? NOOBJ_SCALE : 0.0f);
    float r = w * d * d;

    if (obj) {
        float doff = to - po;
        r += COORD_SCALE * doff * doff;
        float dd = sqrtf(td) - sqrtf(pd);
        r += COORD_SCALE * dd * dd;
    }
    if (do_cls) {
        float x0, x1, x2;
        int idx;
        if (obj) { x0 = l0; x1 = l1; x2 = l2; idx = (int)tcls; }
        else     { x0 = 0.f; x1 = 0.f; x2 = 0.f; idx = 0; }
        float m = fmaxf(x0, fmaxf(x1, x2));
        float lse = logf(expf(x0 - m) + expf(x1 - m) + expf(x2 - m)) + m;
        float li = (idx == 0) ? x0 : ((idx == 1) ? x1 : x2);
        r += lse - li;   // cross-entropy = logsumexp - logit[target]
    }
    return r;
}

__global__ __launch_bounds__(256) void ensemble_loss_kernel(
        const float* __restrict__ pred,
        const float* __restrict__ target,
        double* __restrict__ acc_ws) {
    // Padded LDS tile: 256*13*4 + 256*9*4 = 22528 B -> 7 blocks/CU
    __shared__ float spred[TPB * PRED_PITCH];
    __shared__ float star[TPB * TGT_PITCH];
    __shared__ float wsum[4];

    const int tid = threadIdx.x;

    // ---- prefetch tile 0 into registers (lane-contiguous float4 loads) ----
    float4 pa0, pa1, pa2, pb0, pb1;
    {
        long long c0 = (long long)blockIdx.x * TPB;
        const float4* __restrict__ pb = (const float4*)pred + c0 * 3;
        const float4* __restrict__ tb = (const float4*)target + c0 * 2;
        pa0 = pb[tid]; pa1 = pb[tid + TPB]; pa2 = pb[tid + 2 * TPB];
        pb0 = tb[tid]; pb1 = tb[tid + TPB];
    }

    float acc = 0.0f;
    long long tile = blockIdx.x;
    #pragma unroll 1
    for (int t = 0; t < TILES; ++t) {
        if (t > 0) __syncthreads();   // previous tile's compute done reading LDS

        // ---- scatter prefetched registers into padded LDS ----
        {
            float4 v; int g, cell, sub, a;
            v = pa0; g = tid;           cell = g / 3; sub = g - 3 * cell; a = cell * PRED_PITCH + 4 * sub;
            spred[a+0] = v.x; spred[a+1] = v.y; spred[a+2] = v.z; spred[a+3] = v.w;
            v = pa1; g = tid + TPB;     cell = g / 3; sub = g - 3 * cell; a = cell * PRED_PITCH + 4 * sub;
            spred[a+0] = v.x; spred[a+1] = v.y; spred[a+2] = v.z; spred[a+3] = v.w;
            v = pa2; g = tid + 2 * TPB; cell = g / 3; sub = g - 3 * cell; a = cell * PRED_PITCH + 4 * sub;
            spred[a+0] = v.x; spred[a+1] = v.y; spred[a+2] = v.z; spred[a+3] = v.w;
            v = pb0; g = tid;           cell = g >> 1; sub = g & 1;      a = cell * TGT_PITCH + 4 * sub;
            star[a+0] = v.x; star[a+1] = v.y; star[a+2] = v.z; star[a+3] = v.w;
            v = pb1; g = tid + TPB;     cell = g >> 1; sub = g & 1;      a = cell * TGT_PITCH + 4 * sub;
            star[a+0] = v.x; star[a+1] = v.y; star[a+2] = v.z; star[a+3] = v.w;
        }
        __syncthreads();              // LDS writes visible (vmcnt empty here)

        // ---- issue next tile's loads NOW; they fly during compute below ----
        long long ntile = tile + NBLOCKS;
        if (t + 1 < TILES) {
            long long c0 = ntile * TPB;
            const float4* __restrict__ pb = (const float4*)pred + c0 * 3;
            const float4* __restrict__ tb = (const float4*)target + c0 * 2;
            pa0 = pb[tid]; pa1 = pb[tid + TPB]; pa2 = pb[tid + 2 * TPB];
            pb0 = tb[tid]; pb1 = tb[tid + TPB];
        }

        // ---- compute this tile from LDS (padded stride: conflict-free) ----
        const float* P = &spred[tid * PRED_PITCH];
        const float* T = &star[tid * TGT_PITCH];
        const bool do_cls = (tile * TPB + tid) < CLS_CELLS;
        acc += slot_loss(P[2], P[3], P[4], P[5], P[0], P[1],
                         T[0], T[1], T[2], T[3], do_cls);
        acc += slot_loss(P[8], P[9], P[10], P[11], P[6], P[7],
                         T[4], T[5], T[6], T[7], do_cls);
        tile = ntile;
    }

    // wave(64) shuffle reduction
    for (int off = 32; off > 0; off >>= 1)
        acc += __shfl_down(acc, off, 64);

    int lane = tid & 63;
    int wv = tid >> 6;
    if (lane == 0) wsum[wv] = acc;
    __syncthreads();
    if (tid == 0) {
        float s = wsum[0] + wsum[1] + wsum[2] + wsum[3];
        atomicAdd(&acc_ws[blockIdx.x & (NSLOTS - 1)], (double)s);
    }
}

__global__ void finalize_kernel(const double* __restrict__ acc_ws,
                                float* __restrict__ out) {
    double s = 0.0;
    #pragma unroll
    for (int i = 0; i < NSLOTS; ++i) s += acc_ws[i];
    out[0] = (float)(s * (1.0 / (double)B_SZ));
}

extern "C" void kernel_launch(void* const* d_in, const int* in_sizes, int n_in,
                              void* d_out, int out_size, void* d_ws, size_t ws_size,
                              hipStream_t stream) {
    const float* pred   = (const float*)d_in[0];
    const float* target = (const float*)d_in[1];
    float* out = (float*)d_out;
    double* acc = (double*)d_ws;

    // d_ws is poisoned 0xAA before every launch — zero the accumulator slots.
    hipMemsetAsync(d_ws, 0, NSLOTS * sizeof(double), stream);

    // 2048 blocks x 256 threads x 8 pipelined tiles = 4,194,304 cells.
    ensemble_loss_kernel<<<NBLOCKS, TPB, 0, stream>>>(pred, target, acc);
    finalize_kernel<<<1, 1, 0, stream>>>(acc, out);
}

// Round 5
// 358.509 us; speedup vs baseline: 1.0043x; 1.0043x over previous
//
#include <hip/hip_runtime.h>
#include <math.h>

// Problem constants (from reference)
constexpr int B_SZ = 16384;
constexpr long long CELLS = 4194304;   // 16384*256 cells, 2 anchor slots each
constexpr int CLS_CELLS = 8192;        // logits[:batch_size] -> first 8192 cells get cls loss
constexpr float NOOBJ_SCALE = 0.5f;
constexpr float COORD_SCALE = 5.0f;

constexpr int TPB = 256;               // threads per block == cells per tile
constexpr int NBLOCKS = 2048;
constexpr int TILES = 16384 / NBLOCKS; // 8 tiles per block, interleaved by NBLOCKS
constexpr int NSLOTS = 64;             // atomic scatter slots in d_ws

// Async 16B global->LDS DMA (no VGPR round-trip). LDS dest is wave-uniform
// base + lane*16 — layout must be the raw stream order, no padding.
__device__ __forceinline__ void async_load16(const void* g, void* l) {
    __builtin_amdgcn_global_load_lds(
        (const __attribute__((address_space(1))) unsigned char*)g,
        (__attribute__((address_space(3))) unsigned char*)l,
        16, 0, 0);
}

// Per-(cell,slot) loss contribution.
// pred slot layout: offset=p0, dur=p1, conf=p2, cls=p3..p5  (slot1: +6)
// target slot layout: conf, cls, offset, dur                (slot1: +4)
__device__ __forceinline__ float slot_loss(float pc, float l0, float l1, float l2,
                                           float po, float pd,
                                           float tc, float tcls, float to, float td,
                                           bool do_cls) {
    float d = tc - pc;
    bool obj = (tc == 1.0f);
    float w = obj ? 1.0f : ((tc == 0.0f) ? NOOBJ_SCALE : 0.0f);
    float r = w * d * d;

    if (obj) {
        float doff = to - po;
        r += COORD_SCALE * doff * doff;
        float dd = sqrtf(td) - sqrtf(pd);
        r += COORD_SCALE * dd * dd;
    }
    if (do_cls) {
        float x0, x1, x2;
        int idx;
        if (obj) { x0 = l0; x1 = l1; x2 = l2; idx = (int)tcls; }
        else     { x0 = 0.f; x1 = 0.f; x2 = 0.f; idx = 0; }
        float m = fmaxf(x0, fmaxf(x1, x2));
        float lse = logf(expf(x0 - m) + expf(x1 - m) + expf(x2 - m)) + m;
        float li = (idx == 0) ? x0 : ((idx == 1) ? x1 : x2);
        r += lse - li;   // cross-entropy = logsumexp - logit[target]
    }
    return r;
}

__global__ __launch_bounds__(256) void ensemble_loss_kernel(
        const float* __restrict__ pred,
        const float* __restrict__ target,
        double* __restrict__ acc_ws) {
    // Raw (unpadded) LDS images of the tile: 12 KB pred + 8 KB target.
    __shared__ __align__(16) float spred[TPB * 12];
    __shared__ __align__(16) float star[TPB * 8];
    __shared__ float wsum[4];

    const int tid = threadIdx.x;
    const int wave64 = tid & 192;        // wave_id * 64

    float acc = 0.0f;
    long long tile = blockIdx.x;
    #pragma unroll 1
    for (int t = 0; t < TILES; ++t) {
        if (t > 0) __syncthreads();      // prior compute done reading LDS

        const long long c0 = tile * TPB;
        const float4* __restrict__ pbase = (const float4*)pred + c0 * 3;
        const float4* __restrict__ tbase = (const float4*)target + c0 * 2;

        // ---- DMA the whole tile into LDS: 5 wave-instrs/wave, 16 B/lane ----
        // chunk r covers float4 indices [r*256, r*256+256); LDS word = tile word.
        async_load16(pbase + (0 * TPB + tid), &spred[0 * 1024 + wave64 * 4]);
        async_load16(pbase + (1 * TPB + tid), &spred[1 * 1024 + wave64 * 4]);
        async_load16(pbase + (2 * TPB + tid), &spred[2 * 1024 + wave64 * 4]);
        async_load16(tbase + (0 * TPB + tid), &star [0 * 1024 + wave64 * 4]);
        async_load16(tbase + (1 * TPB + tid), &star [1 * 1024 + wave64 * 4]);

        __syncthreads();                 // vmcnt(0) drain: DMA landed, all waves

        // ---- compute this tile from LDS (raw stride 12/8 words) ----
        const float* P = &spred[tid * 12];
        const float* T = &star[tid * 8];
        const bool do_cls = (c0 + tid) < CLS_CELLS;
        acc += slot_loss(P[2], P[3], P[4], P[5], P[0], P[1],
                         T[0], T[1], T[2], T[3], do_cls);
        acc += slot_loss(P[8], P[9], P[10], P[11], P[6], P[7],
                         T[4], T[5], T[6], T[7], do_cls);
        tile += NBLOCKS;
    }

    // wave(64) shuffle reduction
    for (int off = 32; off > 0; off >>= 1)
        acc += __shfl_down(acc, off, 64);

    int lane = tid & 63;
    int wv = tid >> 6;
    if (lane == 0) wsum[wv] = acc;
    __syncthreads();
    if (tid == 0) {
        float s = wsum[0] + wsum[1] + wsum[2] + wsum[3];
        atomicAdd(&acc_ws[blockIdx.x & (NSLOTS - 1)], (double)s);
    }
}

__global__ void finalize_kernel(const double* __restrict__ acc_ws,
                                float* __restrict__ out) {
    double s = 0.0;
    #pragma unroll
    for (int i = 0; i < NSLOTS; ++i) s += acc_ws[i];
    out[0] = (float)(s * (1.0 / (double)B_SZ));
}

extern "C" void kernel_launch(void* const* d_in, const int* in_sizes, int n_in,
                              void* d_out, int out_size, void* d_ws, size_t ws_size,
                              hipStream_t stream) {
    const float* pred   = (const float*)d_in[0];
    const float* target = (const float*)d_in[1];
    float* out = (float*)d_out;
    double* acc = (double*)d_ws;

    // d_ws is poisoned 0xAA before every launch — zero the accumulator slots.
    hipMemsetAsync(d_ws, 0, NSLOTS * sizeof(double), stream);

    // 2048 blocks x 256 threads x 8 DMA-staged tiles = 4,194,304 cells.
    ensemble_loss_kernel<<<NBLOCKS, TPB, 0, stream>>>(pred, target, acc);
    finalize_kernel<<<1, 1, 0, stream>>>(acc, out);
}